// Round 3
// baseline (201.131 us; speedup 1.0000x reference)
//
#include <hip/hip_runtime.h>
#include <stdint.h>

#define NH 16
#define SEQ 2048
#define DMODEL 1024
#define HD 64
#define NBATCH 2
#define MTOT (NBATCH * SEQ)              // 4096 rows for the big GEMMs
#define QSCALE 0.17677669529663687f      // 1/sqrt(B*H) = 1/sqrt(32)  (faithful bug)

typedef __bf16 bf16x8 __attribute__((ext_vector_type(8)));
typedef __bf16 bf16x4 __attribute__((ext_vector_type(4)));
typedef float f32x4 __attribute__((ext_vector_type(4)));

// round-to-nearest-even fp32 -> bf16 bit pattern
__device__ __forceinline__ unsigned short bf16u(float x) {
  unsigned u = __builtin_bit_cast(unsigned, x);
  u += 0x7fffu + ((u >> 16) & 1u);
  return (unsigned short)(u >> 16);
}

__device__ __forceinline__ f32x4 mfma16(bf16x8 a, bf16x8 b, f32x4 c) {
  return __builtin_amdgcn_mfma_f32_16x16x32_bf16(a, b, c, 0, 0, 0);
}

__device__ __forceinline__ void gl16(const void* g, void* l) {
  __builtin_amdgcn_global_load_lds(
      (const __attribute__((address_space(1))) void*)g,
      (__attribute__((address_space(3))) void*)l, 16, 0, 0);
}

// ---- cast fp32 -> bf16 for queries/keys/values (each 4096x1024) ----
__global__ __launch_bounds__(256) void cast_x_kernel(
    const float* __restrict__ x0, const float* __restrict__ x1,
    const float* __restrict__ x2, unsigned short* __restrict__ o0,
    unsigned short* __restrict__ o1, unsigned short* __restrict__ o2) {
  const float* src = (blockIdx.y == 0) ? x0 : (blockIdx.y == 1) ? x1 : x2;
  unsigned short* dst = (blockIdx.y == 0) ? o0 : (blockIdx.y == 1) ? o1 : o2;
  const int n4 = MTOT * DMODEL / 4;
  for (int i = blockIdx.x * blockDim.x + threadIdx.x; i < n4;
       i += gridDim.x * blockDim.x) {
    float4 f = reinterpret_cast<const float4*>(src)[i];
    ushort4 u;
    u.x = bf16u(f.x); u.y = bf16u(f.y); u.z = bf16u(f.z); u.w = bf16u(f.w);
    reinterpret_cast<ushort4*>(dst)[i] = u;
  }
}

// ---- transpose + cast W (1024x1024 fp32 stored (K,N)) -> Wt bf16 (N,K) ----
__global__ __launch_bounds__(256) void transpose_w_kernel(
    const float* __restrict__ w0, const float* __restrict__ w1,
    const float* __restrict__ w2, const float* __restrict__ w3,
    unsigned short* __restrict__ t0, unsigned short* __restrict__ t1,
    unsigned short* __restrict__ t2, unsigned short* __restrict__ t3) {
  __shared__ float tile[64][65];   // +1 pad: conflict-free column reads
  const float* w = (blockIdx.z == 0) ? w0 : (blockIdx.z == 1) ? w1
                   : (blockIdx.z == 2) ? w2 : w3;
  unsigned short* t = (blockIdx.z == 0) ? t0 : (blockIdx.z == 1) ? t1
                      : (blockIdx.z == 2) ? t2 : t3;
  int k0 = blockIdx.y * 64, n0 = blockIdx.x * 64;
  int tx = threadIdx.x & 63, ty = threadIdx.x >> 6;
#pragma unroll
  for (int i = 0; i < 16; ++i) {
    int kk = ty * 16 + i;
    tile[kk][tx] = w[(k0 + kk) * DMODEL + n0 + tx];   // coalesced read
  }
  __syncthreads();
#pragma unroll
  for (int i = 0; i < 16; ++i) {
    int nn = ty * 16 + i;
    t[(n0 + nn) * DMODEL + k0 + tx] = bf16u(tile[tx][nn]);  // coalesced write
  }
}

// ---- 128x128-tile bf16 GEMM body, 2-phase double-buffered staging ----
// C = A(M,K) @ Wt(N,K)^T, K=1024, N=1024
// mode 0: out bf16, head-split (B,H,S,hd)   (for q, k)
// mode 1: out bf16, head-split transposed (B,H,hd,S)  (for v)
// mode 2: out fp32, plain row-major (M,N)   (final projection)
__device__ __forceinline__ void gemm128_body(
    const unsigned short* __restrict__ A, const unsigned short* __restrict__ Wt,
    unsigned short* __restrict__ outb, float* __restrict__ outf, int mode,
    unsigned short (*lA)[128 * 32], unsigned short (*lB)[128 * 32],
    int bx, int by) {
  const int tid = threadIdx.x;
  const int lane = tid & 63, wid = tid >> 6;
  const int wr = wid >> 1, wc = wid & 1;
  const int m0 = bx * 128, n0 = by * 128;
  const int lm = lane & 15, lg = lane >> 4;
  const int lk = lg * 8;

  auto stage = [&](int buf, int kt) {
#pragma unroll
    for (int i = 0; i < 2; ++i) {
      int c = tid + i * 256;                 // 0..511 16B chunks
      int row = c >> 2, cb = c & 3;
      gl16(A + (m0 + row) * DMODEL + kt * 32 + cb * 8, (char*)lA[buf] + c * 16);
      gl16(Wt + (n0 + row) * DMODEL + kt * 32 + cb * 8, (char*)lB[buf] + c * 16);
    }
  };

  f32x4 acc[4][4] = {};
  stage(0, 0);
  __syncthreads();          // prologue staging complete
  int cur = 0;

  for (int kt = 0; kt < DMODEL / 32; ++kt) {
    if (kt + 1 < DMODEL / 32) stage(cur ^ 1, kt + 1);   // overlap w/ compute

    bf16x8 af[4], bfr[4];
#pragma unroll
    for (int x = 0; x < 4; ++x) {
      af[x] = *reinterpret_cast<const bf16x8*>(&lA[cur][(wr * 64 + x * 16 + lm) * 32 + lk]);
      bfr[x] = *reinterpret_cast<const bf16x8*>(&lB[cur][(wc * 64 + x * 16 + lm) * 32 + lk]);
    }
#pragma unroll
    for (int mi = 0; mi < 4; ++mi)
#pragma unroll
      for (int ni = 0; ni < 4; ++ni)
        acc[mi][ni] = mfma16(af[mi], bfr[ni], acc[mi][ni]);

    if (kt + 1 < DMODEL / 32) {
      __syncthreads();      // stage(kt+1) landed; reads of cur done
      cur ^= 1;
    }
  }

  // epilogue.  C/D layout: col = lane&15, row = (lane>>4)*4 + r
#pragma unroll
  for (int mi = 0; mi < 4; ++mi) {
#pragma unroll
    for (int ni = 0; ni < 4; ++ni) {
      int col = n0 + wc * 64 + ni * 16 + lm;
#pragma unroll
      for (int r = 0; r < 4; ++r) {
        int row = m0 + wr * 64 + mi * 16 + lg * 4 + r;
        float v = acc[mi][ni][r];
        if (mode == 2) {
          outf[row * DMODEL + col] = v;
        } else {
          int b = row >> 11, s = row & (SEQ - 1);
          int h = col >> 6, d = col & (HD - 1);
          int idx = (mode == 0) ? (((b * NH + h) * SEQ + s) * HD + d)
                                : (((b * NH + h) * HD + d) * SEQ + s);
          outb[idx] = bf16u(v);
        }
      }
    }
  }
}

// fused Q/K/V projections: z selects operand set (768 blocks ~ 3/CU)
__global__ __launch_bounds__(256) void gemm_qkv_kernel(
    const unsigned short* __restrict__ xq, const unsigned short* __restrict__ xk,
    const unsigned short* __restrict__ xv,
    const unsigned short* __restrict__ wq, const unsigned short* __restrict__ wk,
    const unsigned short* __restrict__ wv,
    unsigned short* __restrict__ qb, unsigned short* __restrict__ kb,
    unsigned short* __restrict__ vt) {
  __shared__ unsigned short lA[2][128 * 32];
  __shared__ unsigned short lB[2][128 * 32];
  const int z = blockIdx.z;
  const unsigned short* A = (z == 0) ? xq : (z == 1) ? xk : xv;
  const unsigned short* Wt = (z == 0) ? wq : (z == 1) ? wk : wv;
  unsigned short* outb = (z == 0) ? qb : (z == 1) ? kb : vt;
  gemm128_body(A, Wt, outb, nullptr, (z == 2) ? 1 : 0, lA, lB,
               blockIdx.x, blockIdx.y);
}

// final projection
__global__ __launch_bounds__(256) void gemm_out_kernel(
    const unsigned short* __restrict__ A, const unsigned short* __restrict__ Wt,
    float* __restrict__ outf) {
  __shared__ unsigned short lA[2][128 * 32];
  __shared__ unsigned short lB[2][128 * 32];
  gemm128_body(A, Wt, nullptr, outf, 2, lA, lB, blockIdx.x, blockIdx.y);
}

// ---- barrier-free flash attention, swapped QK^T, 1 wave per block ----
// qb, kb: (B,H,S,64) bf16;  vt: (B,H,64,S) bf16;  ao: (B,S,1024) bf16
// grid: 4096 1-wave blocks; XCD-aware decode puts all blocks of a (b,h)
// on one XCD so its 512KB K/V stays in that XCD's L2.
// K-frags for tile kt+1 prefetched during softmax/PV of kt; V-frags for the
// current tile issued right after QK^T so softmax + P-roundtrip hide them.
__global__ __launch_bounds__(64) void attn3_kernel(
    const unsigned short* __restrict__ qb, const unsigned short* __restrict__ kb,
    const unsigned short* __restrict__ vt, const int* __restrict__ vlens,
    unsigned short* __restrict__ ao) {
  __shared__ unsigned short lP[16 * 64];   // P[q][key], XOR-swizzled
  const int lane = threadIdx.x;
  const int lm = lane & 15, lg = lane >> 4;
  const int id = blockIdx.x;
  const int g = id & 7, rem = id >> 3;
  const int sc_ = rem & 127, j = rem >> 7;       // s-chunk, bh/8
  const int bh = j * 8 + g, b = bh >> 4, h = bh & 15;
  const int s0 = sc_ * 16;
  const int q = s0 + lm;
  const int vlen = vlens[b];
  const int nkt = (vlen + 63) >> 6;

  // Q fragments (B-operand: col=q=lm, k = d = lg*8..)
  const unsigned short* qrow = qb + (bh * SEQ + q) * HD;
  bf16x8 qf0 = *reinterpret_cast<const bf16x8*>(qrow + lg * 8);
  bf16x8 qf1 = *reinterpret_cast<const bf16x8*>(qrow + 32 + lg * 8);

  const unsigned short* kbase = kb + bh * SEQ * HD;
  const unsigned short* vbase = vt + (size_t)bh * HD * SEQ;
  char* pbuf = (char*)lP;
  const int swz = (lm & 7) << 4;

  f32x4 oacc[4] = {};          // O^T: oacc[ndb][r] = O[q][ndb*16+lg*4+r]
  float m = -3e38f, l = 0.f;

  // prologue: K-frags for tile 0
  bf16x8 kreg[8];
#pragma unroll
  for (int nb = 0; nb < 4; ++nb) {
    const unsigned short* kr = kbase + (nb * 16 + lm) * HD;
    kreg[nb * 2] = *reinterpret_cast<const bf16x8*>(kr + lg * 8);
    kreg[nb * 2 + 1] = *reinterpret_cast<const bf16x8*>(kr + 32 + lg * 8);
  }

  for (int kt = 0; kt < nkt; ++kt) {
    const int k0 = kt * 64;
    // S^T = K Q^T : sa[nb][r] -> S[q=lm][key = k0 + nb*16 + lg*4 + r]
    f32x4 sa[4];
    __builtin_amdgcn_s_setprio(1);
#pragma unroll
    for (int nb = 0; nb < 4; ++nb) {
      f32x4 z = {};
      z = mfma16(kreg[nb * 2], qf0, z);
      z = mfma16(kreg[nb * 2 + 1], qf1, z);
      sa[nb] = z;
    }
    __builtin_amdgcn_s_setprio(0);

    // V-frags for CURRENT tile (issued first -> oldest in vmcnt queue;
    // PV's counted wait leaves the K prefetch below still in flight)
    bf16x8 vreg[8];
#pragma unroll
    for (int c = 0; c < 2; ++c)
#pragma unroll
      for (int ndb = 0; ndb < 4; ++ndb)
        vreg[c * 4 + ndb] = *reinterpret_cast<const bf16x8*>(
            vbase + (ndb * 16 + lm) * SEQ + k0 + c * 32 + lg * 8);

    // K prefetch for NEXT tile (WAR reuse of kreg)
    const int k0n = (kt + 1 < nkt) ? (kt + 1) * 64 : 0;
#pragma unroll
    for (int nb = 0; nb < 4; ++nb) {
      const unsigned short* kr = kbase + (k0n + nb * 16 + lm) * HD;
      kreg[nb * 2] = *reinterpret_cast<const bf16x8*>(kr + lg * 8);
      kreg[nb * 2 + 1] = *reinterpret_cast<const bf16x8*>(kr + 32 + lg * 8);
    }

    // softmax (in place in sa to cap VGPR)
    const bool lastt = (kt == nkt - 1);
    float tmax = -3e38f;
#pragma unroll
    for (int nb = 0; nb < 4; ++nb)
#pragma unroll
      for (int r = 0; r < 4; ++r) {
        float x = sa[nb][r] * QSCALE;
        if (lastt && (k0 + nb * 16 + lg * 4 + r) >= vlen) x = -1000000.0f;
        sa[nb][r] = x;
        tmax = fmaxf(tmax, x);
      }
    tmax = fmaxf(tmax, __shfl_xor(tmax, 16, 64));
    tmax = fmaxf(tmax, __shfl_xor(tmax, 32, 64));
    float mn = fmaxf(m, tmax);
    float sf = __expf(m - mn);
    m = mn;

    float ps = 0.f;
#pragma unroll
    for (int nb = 0; nb < 4; ++nb)
#pragma unroll
      for (int r = 0; r < 4; ++r) {
        float p = __expf(sa[nb][r] - mn);
        sa[nb][r] = p;
        ps += p;
      }
    ps += __shfl_xor(ps, 16, 64);
    ps += __shfl_xor(ps, 32, 64);
    l = l * sf + ps;
#pragma unroll
    for (int ndb = 0; ndb < 4; ++ndb) oacc[ndb] *= sf;

    // write P[q=lm][key] to LDS (XOR-swizzled rows), transpose-read as A-frag
#pragma unroll
    for (int nb = 0; nb < 4; ++nb) {
      bf16x4 pk;
      pk[0] = (__bf16)sa[nb][0]; pk[1] = (__bf16)sa[nb][1];
      pk[2] = (__bf16)sa[nb][2]; pk[3] = (__bf16)sa[nb][3];
      int off = lm * 128 + (nb * 16 + lg * 4) * 2;
      *reinterpret_cast<bf16x4*>(pbuf + (off ^ swz)) = pk;
    }
    int roff0 = lm * 128 + lg * 16;
    bf16x8 pf0 = *reinterpret_cast<const bf16x8*>(pbuf + (roff0 ^ swz));
    bf16x8 pf1 = *reinterpret_cast<const bf16x8*>(pbuf + ((roff0 + 64) ^ swz));

    // O^T += V^T P^T
    __builtin_amdgcn_s_setprio(1);
#pragma unroll
    for (int ndb = 0; ndb < 4; ++ndb)
      oacc[ndb] = mfma16(vreg[ndb], pf0, oacc[ndb]);
#pragma unroll
    for (int ndb = 0; ndb < 4; ++ndb)
      oacc[ndb] = mfma16(vreg[4 + ndb], pf1, oacc[ndb]);
    __builtin_amdgcn_s_setprio(0);
  }

  const float linv = 1.0f / l;
#pragma unroll
  for (int ndb = 0; ndb < 4; ++ndb) {
    ushort4 o;
    o.x = bf16u(oacc[ndb][0] * linv); o.y = bf16u(oacc[ndb][1] * linv);
    o.z = bf16u(oacc[ndb][2] * linv); o.w = bf16u(oacc[ndb][3] * linv);
    *reinterpret_cast<ushort4*>(
        ao + (b * SEQ + q) * DMODEL + h * HD + ndb * 16 + lg * 4) = o;
  }
}

extern "C" void kernel_launch(void* const* d_in, const int* in_sizes, int n_in,
                              void* d_out, int out_size, void* d_ws, size_t ws_size,
                              hipStream_t stream) {
  (void)in_sizes; (void)n_in; (void)out_size; (void)ws_size;
  const float* q = (const float*)d_in[0];
  const float* k = (const float*)d_in[1];
  const float* v = (const float*)d_in[2];
  const int* vlens = (const int*)d_in[3];
  const float* Wq = (const float*)d_in[4];
  const float* Wk = (const float*)d_in[5];
  const float* Wv = (const float*)d_in[6];
  const float* Wo = (const float*)d_in[7];
  float* out = (float*)d_out;

  char* ws = (char*)d_ws;
  const size_t MB = 1u << 20;
  unsigned short* xq = (unsigned short*)(ws + 0 * MB);   // 8 MB each
  unsigned short* xk = (unsigned short*)(ws + 8 * MB);
  unsigned short* xv = (unsigned short*)(ws + 16 * MB);
  unsigned short* wqt = (unsigned short*)(ws + 24 * MB); // 2 MB each
  unsigned short* wkt = (unsigned short*)(ws + 26 * MB);
  unsigned short* wvt = (unsigned short*)(ws + 28 * MB);
  unsigned short* wot = (unsigned short*)(ws + 30 * MB);
  unsigned short* qb = (unsigned short*)(ws + 32 * MB);  // 8 MB each
  unsigned short* kb = (unsigned short*)(ws + 40 * MB);
  unsigned short* vt = (unsigned short*)(ws + 48 * MB);
  unsigned short* ao = (unsigned short*)(ws + 56 * MB);

  cast_x_kernel<<<dim3(512, 3), 256, 0, stream>>>(q, k, v, xq, xk, xv);
  transpose_w_kernel<<<dim3(16, 16, 4), 256, 0, stream>>>(Wq, Wk, Wv, Wo,
                                                          wqt, wkt, wvt, wot);
  gemm_qkv_kernel<<<dim3(32, 8, 3), 256, 0, stream>>>(xq, xk, xv, wqt, wkt, wvt,
                                                      qb, kb, vt);
  attn3_kernel<<<dim3(4096), 64, 0, stream>>>(qb, kb, vt, vlens, ao);
  gemm_out_kernel<<<dim3(32, 8), 256, 0, stream>>>(ao, wot, out);
}

// Round 5
// 166.530 us; speedup vs baseline: 1.2078x; 1.2078x over previous
//
#include <hip/hip_runtime.h>
#include <stdint.h>

#define NH 16
#define SEQ 2048
#define DMODEL 1024
#define HD 64
#define NBATCH 2
#define MTOT (NBATCH * SEQ)              // 4096 rows for the big GEMMs
#define QSCALE 0.17677669529663687f      // 1/sqrt(B*H) = 1/sqrt(32)  (faithful bug)

typedef __bf16 bf16x8 __attribute__((ext_vector_type(8)));
typedef __bf16 bf16x4 __attribute__((ext_vector_type(4)));
typedef float f32x4 __attribute__((ext_vector_type(4)));
typedef float f32x16 __attribute__((ext_vector_type(16)));
typedef unsigned uint4v __attribute__((ext_vector_type(4)));

// round-to-nearest-even fp32 -> bf16 bit pattern
__device__ __forceinline__ unsigned short bf16u(float x) {
  unsigned u = __builtin_bit_cast(unsigned, x);
  u += 0x7fffu + ((u >> 16) & 1u);
  return (unsigned short)(u >> 16);
}

__device__ __forceinline__ f32x4 mfma16(bf16x8 a, bf16x8 b, f32x4 c) {
  return __builtin_amdgcn_mfma_f32_16x16x32_bf16(a, b, c, 0, 0, 0);
}
__device__ __forceinline__ f32x16 mfma32(bf16x8 a, bf16x8 b, f32x16 c) {
  return __builtin_amdgcn_mfma_f32_32x32x16_bf16(a, b, c, 0, 0, 0);
}

__device__ __forceinline__ void gl16(const void* g, void* l) {
  __builtin_amdgcn_global_load_lds(
      (const __attribute__((address_space(1))) void*)g,
      (__attribute__((address_space(3))) void*)l, 16, 0, 0);
}

// pack 2 f32 -> 2 bf16 in one u32 (lo = a, hi = b)
__device__ __forceinline__ unsigned cvtpk(float a, float b) {
  unsigned r;
  asm("v_cvt_pk_bf16_f32 %0, %1, %2" : "=v"(r) : "v"(a), "v"(b));
  return r;
}

// ---- cast fp32 -> bf16 for queries/keys/values (each 4096x1024) ----
__global__ __launch_bounds__(256) void cast_x_kernel(
    const float* __restrict__ x0, const float* __restrict__ x1,
    const float* __restrict__ x2, unsigned short* __restrict__ o0,
    unsigned short* __restrict__ o1, unsigned short* __restrict__ o2) {
  const float* src = (blockIdx.y == 0) ? x0 : (blockIdx.y == 1) ? x1 : x2;
  unsigned short* dst = (blockIdx.y == 0) ? o0 : (blockIdx.y == 1) ? o1 : o2;
  const int n4 = MTOT * DMODEL / 4;
  for (int i = blockIdx.x * blockDim.x + threadIdx.x; i < n4;
       i += gridDim.x * blockDim.x) {
    float4 f = reinterpret_cast<const float4*>(src)[i];
    ushort4 u;
    u.x = bf16u(f.x); u.y = bf16u(f.y); u.z = bf16u(f.z); u.w = bf16u(f.w);
    reinterpret_cast<ushort4*>(dst)[i] = u;
  }
}

// ---- transpose + cast W (1024x1024 fp32 (K,N)) -> Wt bf16 (N,K) ----
// Wq additionally scaled by QSCALE (folds the score scale into q).
__global__ __launch_bounds__(256) void transpose_w_kernel(
    const float* __restrict__ w0, const float* __restrict__ w1,
    const float* __restrict__ w2, const float* __restrict__ w3,
    unsigned short* __restrict__ t0, unsigned short* __restrict__ t1,
    unsigned short* __restrict__ t2, unsigned short* __restrict__ t3) {
  __shared__ float tile[64][65];   // +1 pad: conflict-free column reads
  const float* w = (blockIdx.z == 0) ? w0 : (blockIdx.z == 1) ? w1
                   : (blockIdx.z == 2) ? w2 : w3;
  unsigned short* t = (blockIdx.z == 0) ? t0 : (blockIdx.z == 1) ? t1
                      : (blockIdx.z == 2) ? t2 : t3;
  const float scl = (blockIdx.z == 0) ? QSCALE : 1.0f;
  int k0 = blockIdx.y * 64, n0 = blockIdx.x * 64;
  int tx = threadIdx.x & 63, ty = threadIdx.x >> 6;
#pragma unroll
  for (int i = 0; i < 16; ++i) {
    int kk = ty * 16 + i;
    tile[kk][tx] = w[(k0 + kk) * DMODEL + n0 + tx];   // coalesced read
  }
  __syncthreads();
#pragma unroll
  for (int i = 0; i < 16; ++i) {
    int nn = ty * 16 + i;
    t[(n0 + nn) * DMODEL + k0 + tx] = bf16u(tile[tx][nn] * scl);
  }
}

// ---- 128x128-tile bf16 GEMM body, 2-phase double-buffered staging ----
// C = A(M,K) @ Wt(N,K)^T, K=1024, N=1024
// mode 0: out bf16, head-split (B,H,S,hd)   (for q, k)
// mode 1: out bf16, head-split transposed (B,H,hd,S)  (for v)
// mode 2: out fp32, plain row-major (M,N)   (final projection)
__device__ __forceinline__ void gemm128_body(
    const unsigned short* __restrict__ A, const unsigned short* __restrict__ Wt,
    unsigned short* __restrict__ outb, float* __restrict__ outf, int mode,
    unsigned short (*lA)[128 * 32], unsigned short (*lB)[128 * 32],
    int bx, int by) {
  const int tid = threadIdx.x;
  const int lane = tid & 63, wid = tid >> 6;
  const int wr = wid >> 1, wc = wid & 1;
  const int m0 = bx * 128, n0 = by * 128;
  const int lm = lane & 15, lg = lane >> 4;
  const int lk = lg * 8;

  auto stage = [&](int buf, int kt) {
#pragma unroll
    for (int i = 0; i < 2; ++i) {
      int c = tid + i * 256;                 // 0..511 16B chunks
      int row = c >> 2, cb = c & 3;
      gl16(A + (m0 + row) * DMODEL + kt * 32 + cb * 8, (char*)lA[buf] + c * 16);
      gl16(Wt + (n0 + row) * DMODEL + kt * 32 + cb * 8, (char*)lB[buf] + c * 16);
    }
  };

  f32x4 acc[4][4] = {};
  stage(0, 0);
  __syncthreads();          // prologue staging complete
  int cur = 0;

  for (int kt = 0; kt < DMODEL / 32; ++kt) {
    if (kt + 1 < DMODEL / 32) stage(cur ^ 1, kt + 1);   // overlap w/ compute

    bf16x8 af[4], bfr[4];
#pragma unroll
    for (int x = 0; x < 4; ++x) {
      af[x] = *reinterpret_cast<const bf16x8*>(&lA[cur][(wr * 64 + x * 16 + lm) * 32 + lk]);
      bfr[x] = *reinterpret_cast<const bf16x8*>(&lB[cur][(wc * 64 + x * 16 + lm) * 32 + lk]);
    }
#pragma unroll
    for (int mi = 0; mi < 4; ++mi)
#pragma unroll
      for (int ni = 0; ni < 4; ++ni)
        acc[mi][ni] = mfma16(af[mi], bfr[ni], acc[mi][ni]);

    if (kt + 1 < DMODEL / 32) {
      __syncthreads();      // stage(kt+1) landed; reads of cur done
      cur ^= 1;
    }
  }

  // epilogue.  C/D layout: col = lane&15, row = (lane>>4)*4 + r
#pragma unroll
  for (int mi = 0; mi < 4; ++mi) {
#pragma unroll
    for (int ni = 0; ni < 4; ++ni) {
      int col = n0 + wc * 64 + ni * 16 + lm;
#pragma unroll
      for (int r = 0; r < 4; ++r) {
        int row = m0 + wr * 64 + mi * 16 + lg * 4 + r;
        float v = acc[mi][ni][r];
        if (mode == 2) {
          outf[row * DMODEL + col] = v;
        } else {
          int b = row >> 11, s = row & (SEQ - 1);
          int h = col >> 6, d = col & (HD - 1);
          int idx = (mode == 0) ? (((b * NH + h) * SEQ + s) * HD + d)
                                : (((b * NH + h) * HD + d) * SEQ + s);
          outb[idx] = bf16u(v);
        }
      }
    }
  }
}

// fused Q/K/V projections: z selects operand set (768 blocks ~ 3/CU)
__global__ __launch_bounds__(256) void gemm_qkv_kernel(
    const unsigned short* __restrict__ xq, const unsigned short* __restrict__ xk,
    const unsigned short* __restrict__ xv,
    const unsigned short* __restrict__ wq, const unsigned short* __restrict__ wk,
    const unsigned short* __restrict__ wv,
    unsigned short* __restrict__ qb, unsigned short* __restrict__ kb,
    unsigned short* __restrict__ vt) {
  __shared__ unsigned short lA[2][128 * 32];
  __shared__ unsigned short lB[2][128 * 32];
  const int z = blockIdx.z;
  const unsigned short* A = (z == 0) ? xq : (z == 1) ? xk : xv;
  const unsigned short* Wt = (z == 0) ? wq : (z == 1) ? wk : wv;
  unsigned short* outb = (z == 0) ? qb : (z == 1) ? kb : vt;
  gemm128_body(A, Wt, outb, nullptr, (z == 2) ? 1 : 0, lA, lB,
               blockIdx.x, blockIdx.y);
}

// final projection
__global__ __launch_bounds__(256) void gemm_out_kernel(
    const unsigned short* __restrict__ A, const unsigned short* __restrict__ Wt,
    float* __restrict__ outf) {
  __shared__ unsigned short lA[2][128 * 32];
  __shared__ unsigned short lB[2][128 * 32];
  gemm128_body(A, Wt, nullptr, outf, 2, lA, lB, blockIdx.x, blockIdx.y);
}

// ---- flash attention: 32x32 MFMA, swapped QK^T, in-register softmax ----
// qb, kb: (B,H,S,64) bf16;  vt: (B,H,64,S) bf16;  ao: (B,S,1024) bf16
// One wave owns 32 q-rows; no LDS, no barriers, no lane exchanges for P.
// Layout-invariance: MFMA contracts A-elem (j,hi) with B-elem (j,hi) through
// the same operand k-slot bijection, so P packed in RAW register order is
// correct as long as V^T elems are loaded with the matching key permutation
// kappa(j,hi) = (j&3) + 8*(j>>2) + 4*hi   (the verified C/D row formula).
// Only HW facts relied on: C/D layout of mfma_f32_32x32x16_bf16 (m74/m101).
__global__ __launch_bounds__(256, 2) void attn6_kernel(
    const unsigned short* __restrict__ qb, const unsigned short* __restrict__ kb,
    const unsigned short* __restrict__ vt, const int* __restrict__ vlens,
    unsigned short* __restrict__ ao) {
  const int lane = threadIdx.x & 63;
  const int qi = lane & 31, hi = lane >> 5;
  const int wid = blockIdx.x * 4 + (threadIdx.x >> 6);
  const int bhi = wid & 31;          // consecutive waves: alternate batches
  const int chunk = wid >> 5;        // 0..63 (32-row q chunk)
  const int b = bhi & 1, h = bhi >> 1;
  const int bh = b * NH + h;
  const int s0w = chunk * 32;
  const int vlen = vlens[b];
  const int nkt = (vlen + 63) >> 6;

  const unsigned short* kbase = kb + bh * SEQ * HD;
  const unsigned short* vbase = vt + (size_t)bh * HD * SEQ;

  // Q fragments (B-operand): col=q=qi, k-slot ks: elems = Q[q][ks*16+hi*8+j]
  const unsigned short* qrow = qb + (bh * SEQ + s0w + qi) * HD;
  bf16x8 qf[4];
#pragma unroll
  for (int ks = 0; ks < 4; ++ks)
    qf[ks] = *reinterpret_cast<const bf16x8*>(qrow + ks * 16 + hi * 8);

  f32x16 oacc[2] = {};     // O^T: col=q, row = d (2 blocks of 32)
  float m = -3e38f, l = 0.f;

  auto loadK = [&](bf16x8* kr, int kt) {
    int k0 = kt * 64;
#pragma unroll
    for (int kb2 = 0; kb2 < 2; ++kb2)
#pragma unroll
      for (int ks = 0; ks < 4; ++ks)
        kr[kb2 * 4 + ks] = *reinterpret_cast<const bf16x8*>(
            kbase + (k0 + kb2 * 32 + qi) * HD + ks * 16 + hi * 8);
  };

  auto body = [&](int kt, bf16x8* kr, bool lastt) {
    const int k0 = kt * 64;
    // S^T = K Q^T : lane (q=qi, hi), reg r of s0/s1 holds
    // S[key = k0 + (32) + (r&3)+8*(r>>2)+4*hi][q]
    f32x16 s0 = {}, s1 = {};
    __builtin_amdgcn_s_setprio(1);
#pragma unroll
    for (int ks = 0; ks < 4; ++ks) s0 = mfma32(kr[ks], qf[ks], s0);
#pragma unroll
    for (int ks = 0; ks < 4; ++ks) s1 = mfma32(kr[4 + ks], qf[ks], s1);
    __builtin_amdgcn_s_setprio(0);

    // V^T A-frags for current tile, loaded with the kappa key permutation:
    // frag f, elem j <- V^T[d][k0 + 16f + (j&3)+8*(j>>2)+4*hi]
    //   elems 0..3: keys 16f+4hi+0..3   (8B)    elems 4..7: +8 (8B)
    bf16x8 vr[8];
#pragma unroll
    for (int db = 0; db < 2; ++db)
#pragma unroll
      for (int f = 0; f < 4; ++f) {
        const unsigned short* vp =
            vbase + (db * 32 + qi) * SEQ + k0 + f * 16 + hi * 4;
        bf16x4 lo4 = *reinterpret_cast<const bf16x4*>(vp);
        bf16x4 hi4 = *reinterpret_cast<const bf16x4*>(vp + 8);
        vr[db * 4 + f] =
            __builtin_shufflevector(lo4, hi4, 0, 1, 2, 3, 4, 5, 6, 7);
      }

    if (lastt) {
#pragma unroll
      for (int r = 0; r < 16; ++r) {
        int key = k0 + (r & 3) + 8 * (r >> 2) + 4 * hi;
        if (key >= vlen) s0[r] = -1000000.0f;
        if (key + 32 >= vlen) s1[r] = -1000000.0f;
      }
    }

    // row max: 31 in-lane + 1 cross-half shuffle
    float mx = s0[0];
#pragma unroll
    for (int r = 1; r < 16; ++r) mx = fmaxf(mx, s0[r]);
#pragma unroll
    for (int r = 0; r < 16; ++r) mx = fmaxf(mx, s1[r]);
    mx = fmaxf(mx, __shfl_xor(mx, 32, 64));
    float mn = fmaxf(m, mx);
    float sf = __expf(m - mn);
    m = mn;

    // exp + row sum
    float ps = 0.f;
#pragma unroll
    for (int r = 0; r < 16; ++r) { s0[r] = __expf(s0[r] - mn); ps += s0[r]; }
#pragma unroll
    for (int r = 0; r < 16; ++r) { s1[r] = __expf(s1[r] - mn); ps += s1[r]; }
    ps += __shfl_xor(ps, 32, 64);
    l = l * sf + ps;
#pragma unroll
    for (int db = 0; db < 2; ++db) oacc[db] *= sf;

    // P B-frags in RAW register order (no lane exchange; see header comment)
    bf16x8 pf[4];
    auto packP = [&](const f32x16& s, bf16x8* out) {
#pragma unroll
      for (int f = 0; f < 2; ++f) {
        uint4v w;
#pragma unroll
        for (int k2 = 0; k2 < 4; ++k2)
          w[k2] = cvtpk(s[f * 8 + k2 * 2], s[f * 8 + k2 * 2 + 1]);
        out[f] = __builtin_bit_cast(bf16x8, w);
      }
    };
    packP(s0, pf);
    packP(s1, pf + 2);

    // O^T += V^T P
    __builtin_amdgcn_s_setprio(1);
#pragma unroll
    for (int db = 0; db < 2; ++db)
#pragma unroll
      for (int f = 0; f < 4; ++f)
        oacc[db] = mfma32(vr[db * 4 + f], pf[f], oacc[db]);
    __builtin_amdgcn_s_setprio(0);
  };

  bf16x8 krA[8], krB[8];
  loadK(krA, 0);
  for (int t = 0; t < nkt; t += 2) {
    loadK(krB, (t + 1 < nkt) ? t + 1 : t);         // prefetch (clamped)
    body(t, krA, t == nkt - 1);
    if (t + 1 >= nkt) break;
    loadK(krA, (t + 2 < nkt) ? t + 2 : t + 1);     // prefetch (clamped)
    body(t + 1, krB, t + 1 == nkt - 1);
  }

  const float linv = 1.0f / l;
#pragma unroll
  for (int db = 0; db < 2; ++db)
#pragma unroll
    for (int rq = 0; rq < 4; ++rq) {
      ushort4 o;
      o.x = bf16u(oacc[db][rq * 4 + 0] * linv);
      o.y = bf16u(oacc[db][rq * 4 + 1] * linv);
      o.z = bf16u(oacc[db][rq * 4 + 2] * linv);
      o.w = bf16u(oacc[db][rq * 4 + 3] * linv);
      int d = db * 32 + 8 * rq + 4 * hi;
      *reinterpret_cast<ushort4*>(
          ao + (b * SEQ + s0w + qi) * DMODEL + h * HD + d) = o;
    }
}

extern "C" void kernel_launch(void* const* d_in, const int* in_sizes, int n_in,
                              void* d_out, int out_size, void* d_ws, size_t ws_size,
                              hipStream_t stream) {
  (void)in_sizes; (void)n_in; (void)out_size; (void)ws_size;
  const float* q = (const float*)d_in[0];
  const float* k = (const float*)d_in[1];
  const float* v = (const float*)d_in[2];
  const int* vlens = (const int*)d_in[3];
  const float* Wq = (const float*)d_in[4];
  const float* Wk = (const float*)d_in[5];
  const float* Wv = (const float*)d_in[6];
  const float* Wo = (const float*)d_in[7];
  float* out = (float*)d_out;

  char* ws = (char*)d_ws;
  const size_t MB = 1u << 20;
  unsigned short* xq = (unsigned short*)(ws + 0 * MB);   // 8 MB each
  unsigned short* xk = (unsigned short*)(ws + 8 * MB);
  unsigned short* xv = (unsigned short*)(ws + 16 * MB);
  unsigned short* wqt = (unsigned short*)(ws + 24 * MB); // 2 MB each
  unsigned short* wkt = (unsigned short*)(ws + 26 * MB);
  unsigned short* wvt = (unsigned short*)(ws + 28 * MB);
  unsigned short* wot = (unsigned short*)(ws + 30 * MB);
  unsigned short* qb = (unsigned short*)(ws + 32 * MB);  // 8 MB each
  unsigned short* kb = (unsigned short*)(ws + 40 * MB);
  unsigned short* vt = (unsigned short*)(ws + 48 * MB);
  unsigned short* ao = (unsigned short*)(ws + 56 * MB);

  cast_x_kernel<<<dim3(512, 3), 256, 0, stream>>>(q, k, v, xq, xk, xv);
  transpose_w_kernel<<<dim3(16, 16, 4), 256, 0, stream>>>(Wq, Wk, Wv, Wo,
                                                          wqt, wkt, wvt, wot);
  gemm_qkv_kernel<<<dim3(32, 8, 3), 256, 0, stream>>>(xq, xk, xv, wqt, wkt, wvt,
                                                      qb, kb, vt);
  attn6_kernel<<<dim3(512), 256, 0, stream>>>(qb, kb, vt, vlens, ao);
  gemm_out_kernel<<<dim3(32, 8), 256, 0, stream>>>(ao, wot, out);
}

// Round 7
// 132.547 us; speedup vs baseline: 1.5174x; 1.2564x over previous
//
#include <hip/hip_runtime.h>
#include <stdint.h>

#define NH 16
#define SEQ 2048
#define DMODEL 1024
#define HD 64
#define NBATCH 2
#define MTOT (NBATCH * SEQ)              // 4096 rows for the big GEMMs
#define QSCALE 0.17677669529663687f      // 1/sqrt(B*H) = 1/sqrt(32)  (faithful bug)
#define LOG2E 1.4426950408889634f

typedef __bf16 bf16x8 __attribute__((ext_vector_type(8)));
typedef __bf16 bf16x4 __attribute__((ext_vector_type(4)));
typedef float f32x4 __attribute__((ext_vector_type(4)));
typedef float f32x16 __attribute__((ext_vector_type(16)));
typedef unsigned uint4v __attribute__((ext_vector_type(4)));

// round-to-nearest-even fp32 -> bf16 bit pattern
__device__ __forceinline__ unsigned short bf16u(float x) {
  unsigned u = __builtin_bit_cast(unsigned, x);
  u += 0x7fffu + ((u >> 16) & 1u);
  return (unsigned short)(u >> 16);
}

// 2^x via v_exp_f32 (ISA: D = 2^S0) — avoids glibc __exp2f macro collision
__device__ __forceinline__ float exp2_fast(float x) {
  float r;
  asm("v_exp_f32 %0, %1" : "=v"(r) : "v"(x));
  return r;
}

__device__ __forceinline__ f32x4 mfma16(bf16x8 a, bf16x8 b, f32x4 c) {
  return __builtin_amdgcn_mfma_f32_16x16x32_bf16(a, b, c, 0, 0, 0);
}
__device__ __forceinline__ f32x16 mfma32(bf16x8 a, bf16x8 b, f32x16 c) {
  return __builtin_amdgcn_mfma_f32_32x32x16_bf16(a, b, c, 0, 0, 0);
}

__device__ __forceinline__ void gl16(const void* g, void* l) {
  __builtin_amdgcn_global_load_lds(
      (const __attribute__((address_space(1))) void*)g,
      (__attribute__((address_space(3))) void*)l, 16, 0, 0);
}

// pack 2 f32 -> 2 bf16 in one u32 (lo = a, hi = b)
__device__ __forceinline__ unsigned cvtpk(float a, float b) {
  unsigned r;
  asm("v_cvt_pk_bf16_f32 %0, %1, %2" : "=v"(r) : "v"(a), "v"(b));
  return r;
}

// ---- cast fp32 -> bf16 for queries/keys/values (each 4096x1024) ----
__global__ __launch_bounds__(256) void cast_x_kernel(
    const float* __restrict__ x0, const float* __restrict__ x1,
    const float* __restrict__ x2, unsigned short* __restrict__ o0,
    unsigned short* __restrict__ o1, unsigned short* __restrict__ o2) {
  const float* src = (blockIdx.y == 0) ? x0 : (blockIdx.y == 1) ? x1 : x2;
  unsigned short* dst = (blockIdx.y == 0) ? o0 : (blockIdx.y == 1) ? o1 : o2;
  const int n4 = MTOT * DMODEL / 4;
  for (int i = blockIdx.x * blockDim.x + threadIdx.x; i < n4;
       i += gridDim.x * blockDim.x) {
    float4 f = reinterpret_cast<const float4*>(src)[i];
    ushort4 u;
    u.x = bf16u(f.x); u.y = bf16u(f.y); u.z = bf16u(f.z); u.w = bf16u(f.w);
    reinterpret_cast<ushort4*>(dst)[i] = u;
  }
}

// ---- transpose + cast W (1024x1024 fp32 (K,N)) -> Wt bf16 (N,K) ----
// Wq additionally scaled by QSCALE*LOG2E (folds score scale + exp2 domain).
__global__ __launch_bounds__(256) void transpose_w_kernel(
    const float* __restrict__ w0, const float* __restrict__ w1,
    const float* __restrict__ w2, const float* __restrict__ w3,
    unsigned short* __restrict__ t0, unsigned short* __restrict__ t1,
    unsigned short* __restrict__ t2, unsigned short* __restrict__ t3) {
  __shared__ float tile[64][65];   // +1 pad: conflict-free column reads
  const float* w = (blockIdx.z == 0) ? w0 : (blockIdx.z == 1) ? w1
                   : (blockIdx.z == 2) ? w2 : w3;
  unsigned short* t = (blockIdx.z == 0) ? t0 : (blockIdx.z == 1) ? t1
                      : (blockIdx.z == 2) ? t2 : t3;
  const float scl = (blockIdx.z == 0) ? QSCALE * LOG2E : 1.0f;
  int k0 = blockIdx.y * 64, n0 = blockIdx.x * 64;
  int tx = threadIdx.x & 63, ty = threadIdx.x >> 6;
#pragma unroll
  for (int i = 0; i < 16; ++i) {
    int kk = ty * 16 + i;
    tile[kk][tx] = w[(k0 + kk) * DMODEL + n0 + tx];   // coalesced read
  }
  __syncthreads();
#pragma unroll
  for (int i = 0; i < 16; ++i) {
    int nn = ty * 16 + i;
    t[(n0 + nn) * DMODEL + k0 + tx] = bf16u(tile[tx][nn] * scl);
  }
}

// ---- 128x128-tile bf16 GEMM body, 2-phase double-buffered staging ----
// C = A(M,K) @ Wt(N,K)^T, K=1024, N=1024
// mode 0: out bf16, head-split (B,H,S,hd)   (for q, k, v)
// mode 2: out fp32, plain row-major (M,N)   (final projection)
__device__ __forceinline__ void gemm128_body(
    const unsigned short* __restrict__ A, const unsigned short* __restrict__ Wt,
    unsigned short* __restrict__ outb, float* __restrict__ outf, int mode,
    unsigned short (*lA)[128 * 32], unsigned short (*lB)[128 * 32],
    int bx, int by) {
  const int tid = threadIdx.x;
  const int lane = tid & 63, wid = tid >> 6;
  const int wr = wid >> 1, wc = wid & 1;
  const int m0 = bx * 128, n0 = by * 128;
  const int lm = lane & 15, lg = lane >> 4;
  const int lk = lg * 8;

  auto stage = [&](int buf, int kt) {
#pragma unroll
    for (int i = 0; i < 2; ++i) {
      int c = tid + i * 256;                 // 0..511 16B chunks
      int row = c >> 2, cb = c & 3;
      gl16(A + (m0 + row) * DMODEL + kt * 32 + cb * 8, (char*)lA[buf] + c * 16);
      gl16(Wt + (n0 + row) * DMODEL + kt * 32 + cb * 8, (char*)lB[buf] + c * 16);
    }
  };

  f32x4 acc[4][4] = {};
  stage(0, 0);
  __syncthreads();          // prologue staging complete
  int cur = 0;

  for (int kt = 0; kt < DMODEL / 32; ++kt) {
    if (kt + 1 < DMODEL / 32) stage(cur ^ 1, kt + 1);   // overlap w/ compute

    bf16x8 af[4], bfr[4];
#pragma unroll
    for (int x = 0; x < 4; ++x) {
      af[x] = *reinterpret_cast<const bf16x8*>(&lA[cur][(wr * 64 + x * 16 + lm) * 32 + lk]);
      bfr[x] = *reinterpret_cast<const bf16x8*>(&lB[cur][(wc * 64 + x * 16 + lm) * 32 + lk]);
    }
#pragma unroll
    for (int mi = 0; mi < 4; ++mi)
#pragma unroll
      for (int ni = 0; ni < 4; ++ni)
        acc[mi][ni] = mfma16(af[mi], bfr[ni], acc[mi][ni]);

    if (kt + 1 < DMODEL / 32) {
      __syncthreads();      // stage(kt+1) landed; reads of cur done
      cur ^= 1;
    }
  }

  // epilogue.  C/D layout: col = lane&15, row = (lane>>4)*4 + r
#pragma unroll
  for (int mi = 0; mi < 4; ++mi) {
#pragma unroll
    for (int ni = 0; ni < 4; ++ni) {
      int col = n0 + wc * 64 + ni * 16 + lm;
#pragma unroll
      for (int r = 0; r < 4; ++r) {
        int row = m0 + wr * 64 + mi * 16 + lg * 4 + r;
        float v = acc[mi][ni][r];
        if (mode == 2) {
          outf[row * DMODEL + col] = v;
        } else {
          int b = row >> 11, s = row & (SEQ - 1);
          int h = col >> 6, d = col & (HD - 1);
          outb[(((b * NH + h) * SEQ + s) * HD + d)] = bf16u(v);
        }
      }
    }
  }
}

// fused Q/K/V projections: z selects operand set (768 blocks ~ 3/CU)
__global__ __launch_bounds__(256) void gemm_qkv_kernel(
    const unsigned short* __restrict__ xq, const unsigned short* __restrict__ xk,
    const unsigned short* __restrict__ xv,
    const unsigned short* __restrict__ wq, const unsigned short* __restrict__ wk,
    const unsigned short* __restrict__ wv,
    unsigned short* __restrict__ qb, unsigned short* __restrict__ kb,
    unsigned short* __restrict__ vb) {
  __shared__ unsigned short lA[2][128 * 32];
  __shared__ unsigned short lB[2][128 * 32];
  const int z = blockIdx.z;
  const unsigned short* A = (z == 0) ? xq : (z == 1) ? xk : xv;
  const unsigned short* Wt = (z == 0) ? wq : (z == 1) ? wk : wv;
  unsigned short* outb = (z == 0) ? qb : (z == 1) ? kb : vb;
  gemm128_body(A, Wt, outb, nullptr, 0, lA, lB, blockIdx.x, blockIdx.y);
}

// final projection
__global__ __launch_bounds__(256) void gemm_out_kernel(
    const unsigned short* __restrict__ A, const unsigned short* __restrict__ Wt,
    float* __restrict__ outf) {
  __shared__ unsigned short lA[2][128 * 32];
  __shared__ unsigned short lB[2][128 * 32];
  gemm128_body(A, Wt, nullptr, outf, 2, lA, lB, blockIdx.x, blockIdx.y);
}

// ---- flash attention: 32x32 MFMA, swapped QK^T, in-register softmax ----
// qb, kb, vb: (B,H,S,64) bf16;  ao: (B,S,1024) bf16
// One wave owns 32 q-rows; no LDS, no barriers, no lane exchanges for P.
// Layout-invariance: MFMA contracts A-slot (j,hi) with B-slot (j,hi) through
// the same operand k-slot bijection, so P packed in RAW register order is
// correct as long as V elems are loaded with the matching key permutation
// kappa(j,hi) = (j&3) + 8*(j>>2) + 4*hi   (the verified C/D row formula).
// V loads are lane-coalesced: lane index runs along d within one key row
// (2 cache lines per instr instead of 64) — fixes the VMEM-transaction-rate
// bound diagnosed in R5.  Scores arrive in log2 domain (Wq pre-scaled).
__global__ __launch_bounds__(256, 2) void attn7_kernel(
    const unsigned short* __restrict__ qb, const unsigned short* __restrict__ kb,
    const unsigned short* __restrict__ vb, const int* __restrict__ vlens,
    unsigned short* __restrict__ ao) {
  const int lane = threadIdx.x & 63;
  const int qi = lane & 31, hi = lane >> 5;
  const int wid = blockIdx.x * 4 + (threadIdx.x >> 6);
  const int bhi = wid & 31;          // consecutive waves: alternate batches
  const int chunk = wid >> 5;        // 0..63 (32-row q chunk)
  const int b = bhi & 1, h = bhi >> 1;
  const int bh = b * NH + h;
  const int s0w = chunk * 32;
  const int vlen = vlens[b];
  const int nkt = (vlen + 63) >> 6;

  const unsigned short* kbase = kb + bh * SEQ * HD;
  const unsigned short* vbase = vb + (size_t)bh * SEQ * HD;

  // Q fragments (B-operand): col=q=qi, k-slot ks: elems = Q[q][ks*16+hi*8+j]
  const unsigned short* qrow = qb + (bh * SEQ + s0w + qi) * HD;
  bf16x8 qf[4];
#pragma unroll
  for (int ks = 0; ks < 4; ++ks)
    qf[ks] = *reinterpret_cast<const bf16x8*>(qrow + ks * 16 + hi * 8);

  f32x16 oacc[2] = {};     // O^T: col=q, row = d (2 blocks of 32)
  float m = -3e38f, l = 0.f;

  auto loadK = [&](bf16x8* kr, int kt) {
    int k0 = kt * 64;
#pragma unroll
    for (int kb2 = 0; kb2 < 2; ++kb2)
#pragma unroll
      for (int ks = 0; ks < 4; ++ks)
        kr[kb2 * 4 + ks] = *reinterpret_cast<const bf16x8*>(
            kbase + (k0 + kb2 * 32 + qi) * HD + ks * 16 + hi * 8);
  };

  auto body = [&](int kt, bf16x8* kr, bool lastt) {
    const int k0 = kt * 64;
    // S^T = K Q^T : lane (q=qi, hi), reg r of s0/s1 holds
    // S[key = k0 + (32) + kappa(r,hi)][q]  (log2-domain scores)
    f32x16 s0 = {}, s1 = {};
    __builtin_amdgcn_s_setprio(1);
#pragma unroll
    for (int ks = 0; ks < 4; ++ks) s0 = mfma32(kr[ks], qf[ks], s0);
#pragma unroll
    for (int ks = 0; ks < 4; ++ks) s1 = mfma32(kr[4 + ks], qf[ks], s1);
    __builtin_amdgcn_s_setprio(0);

    // V A-frags, lane-coalesced scalar loads with kappa key permutation:
    // frag (db,f), elem j <- V[k0 + 16f + kappa(j,hi)][d = db*32 + qi]
    bf16x8 vr[8];
#pragma unroll
    for (int db = 0; db < 2; ++db)
#pragma unroll
      for (int f = 0; f < 4; ++f) {
        const unsigned short* vp =
            vbase + (size_t)(k0 + f * 16 + 4 * hi) * HD + db * 32 + qi;
        bf16x8 t;
#pragma unroll
        for (int j = 0; j < 8; ++j) {
          int koff = ((j & 3) + 8 * (j >> 2)) * HD;
          t[j] = *reinterpret_cast<const __bf16*>(vp + koff);
        }
        vr[db * 4 + f] = t;
      }

    if (lastt) {
#pragma unroll
      for (int r = 0; r < 16; ++r) {
        int key = k0 + (r & 3) + 8 * (r >> 2) + 4 * hi;
        if (key >= vlen) s0[r] = -1.4426950e6f;       // MASK_VALUE * log2e
        if (key + 32 >= vlen) s1[r] = -1.4426950e6f;
      }
    }

    // row max: tree (depth ~5) + 1 cross-half shuffle
    float mx8[8];
#pragma unroll
    for (int i = 0; i < 8; ++i)
      mx8[i] = fmaxf(fmaxf(s0[i], s0[i + 8]), fmaxf(s1[i], s1[i + 8]));
#pragma unroll
    for (int st = 4; st; st >>= 1)
#pragma unroll
      for (int i = 0; i < st; ++i) mx8[i] = fmaxf(mx8[i], mx8[i + st]);
    float mx = fmaxf(mx8[0], __shfl_xor(mx8[0], 32, 64));
    float mn = fmaxf(m, mx);
    float sf = exp2_fast(m - mn);
    m = mn;

    // exp2 + row sum (tree)
#pragma unroll
    for (int r = 0; r < 16; ++r) s0[r] = exp2_fast(s0[r] - mn);
#pragma unroll
    for (int r = 0; r < 16; ++r) s1[r] = exp2_fast(s1[r] - mn);
    float sm8[8];
#pragma unroll
    for (int i = 0; i < 8; ++i)
      sm8[i] = (s0[i] + s0[i + 8]) + (s1[i] + s1[i + 8]);
#pragma unroll
    for (int st = 4; st; st >>= 1)
#pragma unroll
      for (int i = 0; i < st; ++i) sm8[i] += sm8[i + st];
    float ps = sm8[0] + __shfl_xor(sm8[0], 32, 64);
    l = l * sf + ps;
#pragma unroll
    for (int db = 0; db < 2; ++db) oacc[db] *= sf;

    // P B-frags in RAW register order (no lane exchange; see header comment)
    bf16x8 pf[4];
    auto packP = [&](const f32x16& s, bf16x8* out) {
#pragma unroll
      for (int f = 0; f < 2; ++f) {
        uint4v w;
#pragma unroll
        for (int k2 = 0; k2 < 4; ++k2)
          w[k2] = cvtpk(s[f * 8 + k2 * 2], s[f * 8 + k2 * 2 + 1]);
        out[f] = __builtin_bit_cast(bf16x8, w);
      }
    };
    packP(s0, pf);
    packP(s1, pf + 2);

    // O^T += V^T P
    __builtin_amdgcn_s_setprio(1);
#pragma unroll
    for (int db = 0; db < 2; ++db)
#pragma unroll
      for (int f = 0; f < 4; ++f)
        oacc[db] = mfma32(vr[db * 4 + f], pf[f], oacc[db]);
    __builtin_amdgcn_s_setprio(0);
  };

  bf16x8 krA[8], krB[8];
  loadK(krA, 0);
  for (int t = 0; t < nkt; t += 2) {
    loadK(krB, (t + 1 < nkt) ? t + 1 : t);         // prefetch (clamped)
    body(t, krA, t == nkt - 1);
    if (t + 1 >= nkt) break;
    loadK(krA, (t + 2 < nkt) ? t + 2 : t + 1);     // prefetch (clamped)
    body(t + 1, krB, t + 1 == nkt - 1);
  }

  const float linv = 1.0f / l;
#pragma unroll
  for (int db = 0; db < 2; ++db)
#pragma unroll
    for (int rq = 0; rq < 4; ++rq) {
      ushort4 o;
      o.x = bf16u(oacc[db][rq * 4 + 0] * linv);
      o.y = bf16u(oacc[db][rq * 4 + 1] * linv);
      o.z = bf16u(oacc[db][rq * 4 + 2] * linv);
      o.w = bf16u(oacc[db][rq * 4 + 3] * linv);
      int d = db * 32 + 8 * rq + 4 * hi;
      *reinterpret_cast<ushort4*>(
          ao + (b * SEQ + s0w + qi) * DMODEL + h * HD + d) = o;
    }
}

extern "C" void kernel_launch(void* const* d_in, const int* in_sizes, int n_in,
                              void* d_out, int out_size, void* d_ws, size_t ws_size,
                              hipStream_t stream) {
  (void)in_sizes; (void)n_in; (void)out_size; (void)ws_size;
  const float* q = (const float*)d_in[0];
  const float* k = (const float*)d_in[1];
  const float* v = (const float*)d_in[2];
  const int* vlens = (const int*)d_in[3];
  const float* Wq = (const float*)d_in[4];
  const float* Wk = (const float*)d_in[5];
  const float* Wv = (const float*)d_in[6];
  const float* Wo = (const float*)d_in[7];
  float* out = (float*)d_out;

  char* ws = (char*)d_ws;
  const size_t MB = 1u << 20;
  unsigned short* xq = (unsigned short*)(ws + 0 * MB);   // 8 MB each
  unsigned short* xk = (unsigned short*)(ws + 8 * MB);
  unsigned short* xv = (unsigned short*)(ws + 16 * MB);
  unsigned short* wqt = (unsigned short*)(ws + 24 * MB); // 2 MB each
  unsigned short* wkt = (unsigned short*)(ws + 26 * MB);
  unsigned short* wvt = (unsigned short*)(ws + 28 * MB);
  unsigned short* wot = (unsigned short*)(ws + 30 * MB);
  unsigned short* qb = (unsigned short*)(ws + 32 * MB);  // 8 MB each
  unsigned short* kb = (unsigned short*)(ws + 40 * MB);
  unsigned short* vb = (unsigned short*)(ws + 48 * MB);
  unsigned short* ao = (unsigned short*)(ws + 56 * MB);

  cast_x_kernel<<<dim3(512, 3), 256, 0, stream>>>(q, k, v, xq, xk, xv);
  transpose_w_kernel<<<dim3(16, 16, 4), 256, 0, stream>>>(Wq, Wk, Wv, Wo,
                                                          wqt, wkt, wvt, wot);
  gemm_qkv_kernel<<<dim3(32, 8, 3), 256, 0, stream>>>(xq, xk, xv, wqt, wkt, wvt,
                                                      qb, kb, vb);
  attn7_kernel<<<dim3(512), 256, 0, stream>>>(qb, kb, vb, vlens, ao);
  gemm_out_kernel<<<dim3(32, 8), 256, 0, stream>>>(ao, wot, out);
}

// Round 9
// 120.514 us; speedup vs baseline: 1.6689x; 1.0998x over previous
//
#include <hip/hip_runtime.h>
#include <stdint.h>

#define NH 16
#define SEQ 2048
#define DMODEL 1024
#define HD 64
#define NBATCH 2
#define MTOT (NBATCH * SEQ)              // 4096 rows for the big GEMMs
#define QSCALE 0.17677669529663687f      // 1/sqrt(B*H) = 1/sqrt(32)  (faithful bug)
#define LOG2E 1.4426950408889634f

typedef __bf16 bf16x8 __attribute__((ext_vector_type(8)));
typedef float f32x4 __attribute__((ext_vector_type(4)));
typedef float f32x16 __attribute__((ext_vector_type(16)));
typedef unsigned uint4v __attribute__((ext_vector_type(4)));

// round-to-nearest-even fp32 -> bf16 bit pattern
__device__ __forceinline__ unsigned short bf16u(float x) {
  unsigned u = __builtin_bit_cast(unsigned, x);
  u += 0x7fffu + ((u >> 16) & 1u);
  return (unsigned short)(u >> 16);
}

// 2^x via v_exp_f32 (ISA: D = 2^S0)
__device__ __forceinline__ float exp2_fast(float x) {
  float r;
  asm("v_exp_f32 %0, %1" : "=v"(r) : "v"(x));
  return r;
}

__device__ __forceinline__ f32x4 mfma16(bf16x8 a, bf16x8 b, f32x4 c) {
  return __builtin_amdgcn_mfma_f32_16x16x32_bf16(a, b, c, 0, 0, 0);
}
__device__ __forceinline__ f32x16 mfma32(bf16x8 a, bf16x8 b, f32x16 c) {
  return __builtin_amdgcn_mfma_f32_32x32x16_bf16(a, b, c, 0, 0, 0);
}

__device__ __forceinline__ void gl16(const void* g, void* l) {
  __builtin_amdgcn_global_load_lds(
      (const __attribute__((address_space(1))) void*)g,
      (__attribute__((address_space(3))) void*)l, 16, 0, 0);
}

// pack 2 f32 -> 2 bf16 in one u32 (lo = a, hi = b)
__device__ __forceinline__ unsigned cvtpk(float a, float b) {
  unsigned r;
  asm("v_cvt_pk_bf16_f32 %0, %1, %2" : "=v"(r) : "v"(a), "v"(b));
  return r;
}

// ---- cast fp32 -> bf16 for queries/keys/values (each 4096x1024) ----
__global__ __launch_bounds__(256) void cast_x_kernel(
    const float* __restrict__ x0, const float* __restrict__ x1,
    const float* __restrict__ x2, unsigned short* __restrict__ o0,
    unsigned short* __restrict__ o1, unsigned short* __restrict__ o2) {
  const float* src = (blockIdx.y == 0) ? x0 : (blockIdx.y == 1) ? x1 : x2;
  unsigned short* dst = (blockIdx.y == 0) ? o0 : (blockIdx.y == 1) ? o1 : o2;
  const int n4 = MTOT * DMODEL / 4;
  for (int i = blockIdx.x * blockDim.x + threadIdx.x; i < n4;
       i += gridDim.x * blockDim.x) {
    float4 f = reinterpret_cast<const float4*>(src)[i];
    ushort4 u;
    u.x = bf16u(f.x); u.y = bf16u(f.y); u.z = bf16u(f.z); u.w = bf16u(f.w);
    reinterpret_cast<ushort4*>(dst)[i] = u;
  }
}

// ---- transpose + cast W (1024x1024 fp32 (K,N)) -> Wt bf16 (N,K) ----
// Wq additionally scaled by QSCALE*LOG2E (folds score scale + exp2 domain).
__global__ __launch_bounds__(256) void transpose_w_kernel(
    const float* __restrict__ w0, const float* __restrict__ w1,
    const float* __restrict__ w2, const float* __restrict__ w3,
    unsigned short* __restrict__ t0, unsigned short* __restrict__ t1,
    unsigned short* __restrict__ t2, unsigned short* __restrict__ t3) {
  __shared__ float tile[64][65];   // +1 pad: conflict-free column reads
  const float* w = (blockIdx.z == 0) ? w0 : (blockIdx.z == 1) ? w1
                   : (blockIdx.z == 2) ? w2 : w3;
  unsigned short* t = (blockIdx.z == 0) ? t0 : (blockIdx.z == 1) ? t1
                      : (blockIdx.z == 2) ? t2 : t3;
  const float scl = (blockIdx.z == 0) ? QSCALE * LOG2E : 1.0f;
  int k0 = blockIdx.y * 64, n0 = blockIdx.x * 64;
  int tx = threadIdx.x & 63, ty = threadIdx.x >> 6;
#pragma unroll
  for (int i = 0; i < 16; ++i) {
    int kk = ty * 16 + i;
    tile[kk][tx] = w[(k0 + kk) * DMODEL + n0 + tx];   // coalesced read
  }
  __syncthreads();
#pragma unroll
  for (int i = 0; i < 16; ++i) {
    int nn = ty * 16 + i;
    t[(n0 + nn) * DMODEL + k0 + tx] = bf16u(tile[tx][nn] * scl);
  }
}

// ---- 128x128-tile bf16 GEMM, 2-phase dbuf staging (q/k/v projections) ----
__global__ __launch_bounds__(256) void gemm_qkv_kernel(
    const unsigned short* __restrict__ xq, const unsigned short* __restrict__ xk,
    const unsigned short* __restrict__ xv,
    const unsigned short* __restrict__ wq, const unsigned short* __restrict__ wk,
    const unsigned short* __restrict__ wv,
    unsigned short* __restrict__ qb, unsigned short* __restrict__ kb,
    unsigned short* __restrict__ vb) {
  __shared__ unsigned short lA[2][128 * 32];
  __shared__ unsigned short lB[2][128 * 32];
  const int z = blockIdx.z;
  const unsigned short* A = (z == 0) ? xq : (z == 1) ? xk : xv;
  const unsigned short* Wt = (z == 0) ? wq : (z == 1) ? wk : wv;
  unsigned short* outb = (z == 0) ? qb : (z == 1) ? kb : vb;

  const int tid = threadIdx.x;
  const int lane = tid & 63, wid = tid >> 6;
  const int wr = wid >> 1, wc = wid & 1;
  const int m0 = blockIdx.x * 128, n0 = blockIdx.y * 128;
  const int lm = lane & 15, lg = lane >> 4;
  const int lk = lg * 8;

  auto stage = [&](int buf, int kt) {
#pragma unroll
    for (int i = 0; i < 2; ++i) {
      int c = tid + i * 256;
      int row = c >> 2, cb = c & 3;
      gl16(A + (m0 + row) * DMODEL + kt * 32 + cb * 8, (char*)lA[buf] + c * 16);
      gl16(Wt + (n0 + row) * DMODEL + kt * 32 + cb * 8, (char*)lB[buf] + c * 16);
    }
  };

  f32x4 acc[4][4] = {};
  stage(0, 0);
  __syncthreads();
  int cur = 0;

  for (int kt = 0; kt < DMODEL / 32; ++kt) {
    if (kt + 1 < DMODEL / 32) stage(cur ^ 1, kt + 1);

    bf16x8 af[4], bfr[4];
#pragma unroll
    for (int x = 0; x < 4; ++x) {
      af[x] = *reinterpret_cast<const bf16x8*>(&lA[cur][(wr * 64 + x * 16 + lm) * 32 + lk]);
      bfr[x] = *reinterpret_cast<const bf16x8*>(&lB[cur][(wc * 64 + x * 16 + lm) * 32 + lk]);
    }
#pragma unroll
    for (int mi = 0; mi < 4; ++mi)
#pragma unroll
      for (int ni = 0; ni < 4; ++ni)
        acc[mi][ni] = mfma16(af[mi], bfr[ni], acc[mi][ni]);

    if (kt + 1 < DMODEL / 32) { __syncthreads(); cur ^= 1; }
  }

#pragma unroll
  for (int mi = 0; mi < 4; ++mi)
#pragma unroll
    for (int ni = 0; ni < 4; ++ni) {
      int col = n0 + wc * 64 + ni * 16 + lm;
#pragma unroll
      for (int r = 0; r < 4; ++r) {
        int row = m0 + wr * 64 + mi * 16 + lg * 4 + r;
        int b = row >> 11, s = row & (SEQ - 1);
        int h = col >> 6, d = col & (HD - 1);
        outb[(((b * NH + h) * SEQ + s) * HD + d)] = bf16u(acc[mi][ni][r]);
      }
    }
}

// ---- final projection: 128x64 tiles (512 blocks, 2/CU) ----
__global__ __launch_bounds__(256) void gemm_out_kernel(
    const unsigned short* __restrict__ A, const unsigned short* __restrict__ Wt,
    float* __restrict__ outf) {
  __shared__ unsigned short lA[2][128 * 32];
  __shared__ unsigned short lB[2][64 * 32];
  const int tid = threadIdx.x;
  const int lane = tid & 63, wr = tid >> 6;    // wave owns 32 m-rows
  const int m0 = blockIdx.x * 128, n0 = blockIdx.y * 64;
  const int lm = lane & 15, lg = lane >> 4;
  const int lk = lg * 8;

  auto stage = [&](int buf, int kt) {
#pragma unroll
    for (int i = 0; i < 2; ++i) {
      int c = tid + i * 256;
      int row = c >> 2, cb = c & 3;
      gl16(A + (m0 + row) * DMODEL + kt * 32 + cb * 8, (char*)lA[buf] + c * 16);
    }
    int c = tid;
    int row = c >> 2, cb = c & 3;
    gl16(Wt + (n0 + row) * DMODEL + kt * 32 + cb * 8, (char*)lB[buf] + c * 16);
  };

  f32x4 acc[2][4] = {};
  stage(0, 0);
  __syncthreads();
  int cur = 0;

  for (int kt = 0; kt < DMODEL / 32; ++kt) {
    if (kt + 1 < DMODEL / 32) stage(cur ^ 1, kt + 1);

    bf16x8 af[2], bfr[4];
#pragma unroll
    for (int x = 0; x < 2; ++x)
      af[x] = *reinterpret_cast<const bf16x8*>(&lA[cur][(wr * 32 + x * 16 + lm) * 32 + lk]);
#pragma unroll
    for (int x = 0; x < 4; ++x)
      bfr[x] = *reinterpret_cast<const bf16x8*>(&lB[cur][(x * 16 + lm) * 32 + lk]);
#pragma unroll
    for (int mi = 0; mi < 2; ++mi)
#pragma unroll
      for (int ni = 0; ni < 4; ++ni)
        acc[mi][ni] = mfma16(af[mi], bfr[ni], acc[mi][ni]);

    if (kt + 1 < DMODEL / 32) { __syncthreads(); cur ^= 1; }
  }

#pragma unroll
  for (int mi = 0; mi < 2; ++mi)
#pragma unroll
    for (int ni = 0; ni < 4; ++ni) {
      int col = n0 + ni * 16 + lm;
#pragma unroll
      for (int r = 0; r < 4; ++r) {
        int row = m0 + wr * 32 + mi * 16 + lg * 4 + r;
        outf[row * DMODEL + col] = acc[mi][ni][r];
      }
    }
}

// ---- flash attention: 32x32 MFMA, swapped QK^T, K via swizzled LDS ----
// qb, kb, vb: (B,H,S,64) bf16;  ao: (B,S,1024) bf16
// One wave owns 32 q-rows; no barriers (per-wave LDS, K double-buffered).
// K staged coalesced via global_load_lds (linear dest) with the global source
// column pre-XOR-permuted (m173/m201 both-sides pattern); ds_read_b128 frag
// reads use byte col ^ ((row&7)<<4).  This cuts K's per-tile cache-line
// transactions 256 -> ~16 (R7 diagnosis: K frag loads strided 128B/lane were
// the L2-transaction bottleneck).  V stays as R7's lane-coalesced scalar
// loads with the kappa key permutation (bench-validated).
__global__ __launch_bounds__(256, 2) void attn9_kernel(
    const unsigned short* __restrict__ qb, const unsigned short* __restrict__ kb,
    const unsigned short* __restrict__ vb, const int* __restrict__ vlens,
    unsigned short* __restrict__ ao) {
  __shared__ char klds[4][2][8192];   // [wave][buf][64 keys x 128B], swizzled
  const int lane = threadIdx.x & 63;
  const int w = threadIdx.x >> 6;
  const int qi = lane & 31, hi = lane >> 5;
  const int wid = blockIdx.x * 4 + w;
  const int bhi = wid & 31;          // consecutive waves: alternate batches
  const int chunk = wid >> 5;        // 0..63 (32-row q chunk)
  const int b = bhi & 1, h = bhi >> 1;
  const int bh = b * NH + h;
  const int s0w = chunk * 32;
  const int vlen = vlens[b];
  const int nkt = (vlen + 63) >> 6;

  const unsigned short* kbase = kb + bh * SEQ * HD;
  const unsigned short* vbase = vb + (size_t)bh * SEQ * HD;

  // Q fragments (B-operand): col=q=qi, k-slot ks: elems = Q[q][ks*16+hi*8+j]
  const unsigned short* qrow = qb + (bh * SEQ + s0w + qi) * HD;
  bf16x8 qf[4];
#pragma unroll
  for (int ks = 0; ks < 4; ++ks)
    qf[ks] = *reinterpret_cast<const bf16x8*>(qrow + ks * 16 + hi * 8);

  f32x16 oacc[2] = {};     // O^T: col=q, row = d (2 blocks of 32)
  float m = -3e38f, l = 0.f;

  // K staging: instr i, lane L -> LDS linear byte i*1024 + L*16
  //  = row (i*8 + (L>>3)), colS (L&7)*16.  Want LDS[row][colS] to hold
  //  K[row][colS ^ ((row&7)<<4)] -> global col8 = (L&7) ^ ((L>>3)&7).
  const int srow = lane >> 3;                 // 0..7
  const int scol8 = (lane & 7) ^ (srow & 7);  // pre-swizzled source col
  auto stageK = [&](int buf, int kt) {
    int k0 = kt * 64;
    char* dst = &klds[w][buf][0];
#pragma unroll
    for (int i = 0; i < 8; ++i)
      gl16(kbase + (size_t)(k0 + i * 8 + srow) * HD + scol8 * 8,
           dst + i * 1024);
  };

  // frag read: row = kb2*32+qi, byte col = (ks*32+hi*16) ^ ((qi&7)<<4)
  auto readK = [&](bf16x8* kr, int buf) {
    const char* base = &klds[w][buf][0];
#pragma unroll
    for (int kb2 = 0; kb2 < 2; ++kb2)
#pragma unroll
      for (int ks = 0; ks < 4; ++ks) {
        int row = kb2 * 32 + qi;
        int off = row * 128 + ((ks * 32 + hi * 16) ^ ((qi & 7) << 4));
        kr[kb2 * 4 + ks] = *reinterpret_cast<const bf16x8*>(base + off);
      }
  };

  auto body = [&](int t, int buf) {
    const int k0 = t * 64;
    const bool lastt = (t == nkt - 1);

    // K(t) staging (gl16, no register def) must complete before ds_reads;
    // compiler can't track this dependency -> explicit wait + pin (rule #18).
    asm volatile("s_waitcnt vmcnt(0)" ::: "memory");
    __builtin_amdgcn_sched_barrier(0);

    bf16x8 kr[8];
    readK(kr, buf);

    // S^T = K Q^T : lane (q=qi, hi), reg r holds S[key=k0+(32)+g(r,hi)][q]
    f32x16 s0 = {}, s1 = {};
    __builtin_amdgcn_s_setprio(1);
#pragma unroll
    for (int ks = 0; ks < 4; ++ks) s0 = mfma32(kr[ks], qf[ks], s0);
#pragma unroll
    for (int ks = 0; ks < 4; ++ks) s1 = mfma32(kr[4 + ks], qf[ks], s1);
    __builtin_amdgcn_s_setprio(0);

    // prefetch K(t+1) FIRST (oldest in vmcnt queue), then V(t) scalars
    if (!lastt) stageK(buf ^ 1, t + 1);

    // V A-frags, lane-coalesced scalar loads with kappa key permutation:
    // frag (db,f), elem j <- V[k0 + 16f + g(j,hi)][d = db*32 + qi]
    bf16x8 vr[8];
#pragma unroll
    for (int db = 0; db < 2; ++db)
#pragma unroll
      for (int f = 0; f < 4; ++f) {
        const unsigned short* vp =
            vbase + (size_t)(k0 + f * 16 + 4 * hi) * HD + db * 32 + qi;
        bf16x8 tv;
#pragma unroll
        for (int j = 0; j < 8; ++j) {
          int koff = ((j & 3) + 8 * (j >> 2)) * HD;
          tv[j] = *reinterpret_cast<const __bf16*>(vp + koff);
        }
        vr[db * 4 + f] = tv;
      }

    if (lastt) {
#pragma unroll
      for (int r = 0; r < 16; ++r) {
        int key = k0 + (r & 3) + 8 * (r >> 2) + 4 * hi;
        if (key >= vlen) s0[r] = -1.4426950e6f;       // MASK_VALUE * log2e
        if (key + 32 >= vlen) s1[r] = -1.4426950e6f;
      }
    }

    // row max: tree + 1 cross-half shuffle
    float mx8[8];
#pragma unroll
    for (int i = 0; i < 8; ++i)
      mx8[i] = fmaxf(fmaxf(s0[i], s0[i + 8]), fmaxf(s1[i], s1[i + 8]));
#pragma unroll
    for (int st = 4; st; st >>= 1)
#pragma unroll
      for (int i = 0; i < st; ++i) mx8[i] = fmaxf(mx8[i], mx8[i + st]);
    float mx = fmaxf(mx8[0], __shfl_xor(mx8[0], 32, 64));
    float mn = fmaxf(m, mx);
    float sf = exp2_fast(m - mn);
    m = mn;

    // exp2 + row sum (tree)
#pragma unroll
    for (int r = 0; r < 16; ++r) s0[r] = exp2_fast(s0[r] - mn);
#pragma unroll
    for (int r = 0; r < 16; ++r) s1[r] = exp2_fast(s1[r] - mn);
    float sm8[8];
#pragma unroll
    for (int i = 0; i < 8; ++i)
      sm8[i] = (s0[i] + s0[i + 8]) + (s1[i] + s1[i + 8]);
#pragma unroll
    for (int st = 4; st; st >>= 1)
#pragma unroll
      for (int i = 0; i < st; ++i) sm8[i] += sm8[i + st];
    float ps = sm8[0] + __shfl_xor(sm8[0], 32, 64);
    l = l * sf + ps;
#pragma unroll
    for (int db = 0; db < 2; ++db) oacc[db] *= sf;

    // P B-frags in RAW register order (layout-invariance, R7-validated)
    bf16x8 pf[4];
    auto packP = [&](const f32x16& s, bf16x8* out) {
#pragma unroll
      for (int f = 0; f < 2; ++f) {
        uint4v wv;
#pragma unroll
        for (int k2 = 0; k2 < 4; ++k2)
          wv[k2] = cvtpk(s[f * 8 + k2 * 2], s[f * 8 + k2 * 2 + 1]);
        out[f] = __builtin_bit_cast(bf16x8, wv);
      }
    };
    packP(s0, pf);
    packP(s1, pf + 2);

    // O^T += V^T P
    __builtin_amdgcn_s_setprio(1);
#pragma unroll
    for (int db = 0; db < 2; ++db)
#pragma unroll
      for (int f = 0; f < 4; ++f)
        oacc[db] = mfma32(vr[db * 4 + f], pf[f], oacc[db]);
    __builtin_amdgcn_s_setprio(0);
  };

  stageK(0, 0);
  for (int t = 0; t < nkt; ++t) body(t, t & 1);

  const float linv = 1.0f / l;
#pragma unroll
  for (int db = 0; db < 2; ++db)
#pragma unroll
    for (int rq = 0; rq < 4; ++rq) {
      ushort4 o;
      o.x = bf16u(oacc[db][rq * 4 + 0] * linv);
      o.y = bf16u(oacc[db][rq * 4 + 1] * linv);
      o.z = bf16u(oacc[db][rq * 4 + 2] * linv);
      o.w = bf16u(oacc[db][rq * 4 + 3] * linv);
      int d = db * 32 + 8 * rq + 4 * hi;
      *reinterpret_cast<ushort4*>(
          ao + (b * SEQ + s0w + qi) * DMODEL + h * HD + d) = o;
    }
}

extern "C" void kernel_launch(void* const* d_in, const int* in_sizes, int n_in,
                              void* d_out, int out_size, void* d_ws, size_t ws_size,
                              hipStream_t stream) {
  (void)in_sizes; (void)n_in; (void)out_size; (void)ws_size;
  const float* q = (const float*)d_in[0];
  const float* k = (const float*)d_in[1];
  const float* v = (const float*)d_in[2];
  const int* vlens = (const int*)d_in[3];
  const float* Wq = (const float*)d_in[4];
  const float* Wk = (const float*)d_in[5];
  const float* Wv = (const float*)d_in[6];
  const float* Wo = (const float*)d_in[7];
  float* out = (float*)d_out;

  char* ws = (char*)d_ws;
  const size_t MB = 1u << 20;
  unsigned short* xq = (unsigned short*)(ws + 0 * MB);   // 8 MB each
  unsigned short* xk = (unsigned short*)(ws + 8 * MB);
  unsigned short* xv = (unsigned short*)(ws + 16 * MB);
  unsigned short* wqt = (unsigned short*)(ws + 24 * MB); // 2 MB each
  unsigned short* wkt = (unsigned short*)(ws + 26 * MB);
  unsigned short* wvt = (unsigned short*)(ws + 28 * MB);
  unsigned short* wot = (unsigned short*)(ws + 30 * MB);
  unsigned short* qb = (unsigned short*)(ws + 32 * MB);  // 8 MB each
  unsigned short* kb = (unsigned short*)(ws + 40 * MB);
  unsigned short* vb = (unsigned short*)(ws + 48 * MB);
  unsigned short* ao = (unsigned short*)(ws + 56 * MB);

  cast_x_kernel<<<dim3(512, 3), 256, 0, stream>>>(q, k, v, xq, xk, xv);
  transpose_w_kernel<<<dim3(16, 16, 4), 256, 0, stream>>>(Wq, Wk, Wv, Wo,
                                                          wqt, wkt, wvt, wot);
  gemm_qkv_kernel<<<dim3(32, 8, 3), 256, 0, stream>>>(xq, xk, xv, wqt, wkt, wvt,
                                                      qb, kb, vb);
  attn9_kernel<<<dim3(512), 256, 0, stream>>>(qb, kb, vb, vlens, ao);
  gemm_out_kernel<<<dim3(32, 16), 256, 0, stream>>>(ao, wot, out);
}